// Round 8
// baseline (180.869 us; speedup 1.0000x reference)
//
#include <hip/hip_runtime.h>
#include <math.h>

// Problem constants
#define NN 1024      // N
#define DD 64        // D
#define TT 2048      // T
#define UDEC 0.97f
#define EPS 1e-6f

// rho/a* path chunking
#define CC 64        // chunk length along t
#define NCH 32       // TT/CC
#define NSL 16       // N-slices
#define SLW 64       // NN/NSL
// X prefix-scan chunking
#define C2 8
#define NC2 256      // TT/C2

#define NTHR 256

// Swizzled [R][64] fp32 LDS tile: element (r,c) at float4-block r*16+((c>>2)^(r&15)).
__device__ __forceinline__ int swz4(int r, int c4) { return r * 16 + (c4 ^ (r & 15)); }

#define DOT4(p, q2) ((p).x*(q2).x + (p).y*(q2).y + (p).z*(q2).z + (p).w*(q2).w)
#define F4ADD(a, b) make_float4((a).x+(b).x, (a).y+(b).y, (a).z+(b).z, (a).w+(b).w)

// ---------------------------------------------------------------------------
// K0: one-shot transposes (runs first, independent of everything else).
//     blocks 0..63:   E[D][N]  -> Et4 [n4][d] float4
//     blocks 64..127: Dx[N][D] -> Dxq [d4][n] float4
//     blocks 128..191:Dy[N][D] -> Dyq [d4][n] float4
__global__ __launch_bounds__(NTHR) void k_prep(
    const float* __restrict__ E, float* __restrict__ Et4,
    const float* __restrict__ Dx, float* __restrict__ Dxq,
    const float* __restrict__ Dy, float* __restrict__ Dyq)
{
    const int b = blockIdx.x, tid = threadIdx.x;
    if (b < 64) {
        const int fi = b * NTHR + tid;                   // n4*64 + d
        const int n4 = fi >> 6, d = fi & 63;
        reinterpret_cast<float4*>(Et4)[fi] =
            reinterpret_cast<const float4*>(E)[d * (NN / 4) + n4];
    } else if (b < 128) {
        const int fi = (b - 64) * NTHR + tid;            // d4*NN + n
        const int d4 = fi >> 10, n = fi & 1023;
        reinterpret_cast<float4*>(Dxq)[fi] =
            reinterpret_cast<const float4*>(Dx)[n * (DD / 4) + d4];
    } else {
        const int fi = (b - 128) * NTHR + tid;
        const int d4 = fi >> 10, n = fi & 1023;
        reinterpret_cast<float4*>(Dyq)[fi] =
            reinterpret_cast<const float4*>(Dy)[n * (DD / 4) + d4];
    }
}

// ---------------------------------------------------------------------------
// K1: X chunk-scan, chunks of C2=8 tokens. 1024 blocks. Coalesced Dxq preload.
__global__ __launch_bounds__(NTHR) void k_xscan(
    const float* __restrict__ Dxq, const float* __restrict__ temb,
    const int* __restrict__ toks, float* __restrict__ Xp, float* __restrict__ S)
{
    __shared__ float Vs[C2][DD];
    const int b = blockIdx.x, tid = threadIdx.x;
    const int cs = b >> 2, qx = b & 3;
    const int n = qx * 256 + tid;
    for (int i = tid; i < C2 * DD / 4; i += NTHR) {
        int s = i >> 4, d4 = i & 15;
        reinterpret_cast<float4*>(&Vs[s][0])[d4] =
            reinterpret_cast<const float4*>(temb + toks[cs * C2 + s] * DD)[d4];
    }
    __syncthreads();
    float dxr[DD];
    const float4* dxq4 = reinterpret_cast<const float4*>(Dxq);
#pragma unroll
    for (int j = 0; j < 16; ++j) {
        float4 v = dxq4[j * NN + n];                     // 1KB/wave coalesced
        dxr[4*j] = v.x; dxr[4*j+1] = v.y; dxr[4*j+2] = v.z; dxr[4*j+3] = v.w;
    }
    float run = 0.f;
    for (int s = 0; s < C2; ++s) {
        const float4* vr = reinterpret_cast<const float4*>(&Vs[s][0]);
        float a0 = 0.f, a1 = 0.f, a2 = 0.f, a3 = 0.f;
#pragma unroll
        for (int j = 0; j < 16; ++j) {
            float4 v = vr[j];
            a0 += v.x * dxr[4*j];     a1 += v.y * dxr[4*j+1];
            a2 += v.z * dxr[4*j+2];   a3 += v.w * dxr[4*j+3];
        }
        run += fmaxf((a0 + a1) + (a2 + a3), 0.f);
        Xp[(cs * C2 + s) * NN + n] = run;
    }
    S[cs * NN + n] = run;
}

// ---------------------------------------------------------------------------
// K2: segmented scan of 256 chunk totals -> exclusive base Bb. 32 blocks.
__global__ __launch_bounds__(NTHR) void k_base(
    const float* __restrict__ S, const float* __restrict__ x0, float* __restrict__ Bb)
{
    __shared__ float ssl[8][33];
    const int b = blockIdx.x, tid = threadIdx.x;
    const int n_l = tid & 31, seg = tid >> 5;            // 8 segs x 32 chunks
    const int n = b * 32 + n_l;
    float m[32];
#pragma unroll
    for (int j = 0; j < 32; ++j) m[j] = S[(seg * 32 + j) * NN + n];
    float tot = 0.f;
#pragma unroll
    for (int j = 0; j < 32; ++j) tot += m[j];
    ssl[seg][n_l] = tot;
    __syncthreads();
    float acc = x0[n];
    for (int r = 0; r < seg; ++r) acc += ssl[r][n_l];
#pragma unroll
    for (int j = 0; j < 32; ++j) {
        Bb[(seg * 32 + j) * NN + n] = acc;               // exclusive prefix + x0
        acc += m[j];
    }
}

// ---------------------------------------------------------------------------
// K3: per (chunk,slice): role0 = M (rank collapse), role1 = Gram. 1024 blocks.
__global__ __launch_bounds__(NTHR) void k_mgram(
    const float* __restrict__ Xp, const float* __restrict__ Bb,
    const float* __restrict__ temb, const int* __restrict__ toks,
    float* __restrict__ M, float* __restrict__ Gp)
{
    __shared__ float Xs[CC * DD];
    __shared__ float Vw[CC * DD];
    __shared__ float pw[CC + 1];
    const int b = blockIdx.x, tid = threadIdx.x;
    const int c = b >> 5, q = (b >> 1) & 15, role = b & 1;
    if (role == 0 && tid <= CC) pw[tid] = powf(UDEC, (float)tid);
    for (int i = tid; i < CC * SLW / 4; i += NTHR) {
        int s = i >> 4, n4 = i & 15;
        int t = c * CC + s;
        float4 xv = *reinterpret_cast<const float4*>(&Xp[t * NN + q * SLW + n4 * 4]);
        float4 bv = *reinterpret_cast<const float4*>(&Bb[(t >> 3) * NN + q * SLW + n4 * 4]);
        reinterpret_cast<float4*>(Xs)[swz4(s, n4)] = F4ADD(xv, bv);
    }
    __syncthreads();
    if (role == 0) {
        for (int i = tid; i < CC * DD / 4; i += NTHR) {
            int s = i >> 4, d4 = i & 15;
            float4 v = reinterpret_cast<const float4*>(temb + toks[c * CC + s] * DD)[d4];
            float wv = pw[CC - s];
            reinterpret_cast<float4*>(Vw)[swz4(s, d4)] =
                make_float4(v.x * wv, v.y * wv, v.z * wv, v.w * wv);
        }
    }
    __syncthreads();
    const float4* Xs4 = reinterpret_cast<const float4*>(Xs);
    if (role == 0) {
        const int dg = tid >> 4, ng = tid & 15;
        float acc[16];
#pragma unroll
        for (int k = 0; k < 16; ++k) acc[k] = 0.f;
        const float4* Vw4 = reinterpret_cast<const float4*>(Vw);
        for (int s = 0; s < CC; ++s) {
            float4 vw = Vw4[swz4(s, dg)];
            float4 xs = Xs4[swz4(s, ng)];
            acc[0]  += vw.x*xs.x; acc[1]  += vw.x*xs.y; acc[2]  += vw.x*xs.z; acc[3]  += vw.x*xs.w;
            acc[4]  += vw.y*xs.x; acc[5]  += vw.y*xs.y; acc[6]  += vw.y*xs.z; acc[7]  += vw.y*xs.w;
            acc[8]  += vw.z*xs.x; acc[9]  += vw.z*xs.y; acc[10] += vw.z*xs.z; acc[11] += vw.z*xs.w;
            acc[12] += vw.w*xs.x; acc[13] += vw.w*xs.y; acc[14] += vw.w*xs.z; acc[15] += vw.w*xs.w;
        }
#pragma unroll
        for (int a = 0; a < 4; ++a)
            *reinterpret_cast<float4*>(&M[(c * DD + dg * 4 + a) * NN + q * SLW + ng * 4]) =
                make_float4(acc[a*4], acc[a*4+1], acc[a*4+2], acc[a*4+3]);
    } else {
        const int tg = tid >> 4, sg = tid & 15;
        float acc[16];
#pragma unroll
        for (int k = 0; k < 16; ++k) acc[k] = 0.f;
        for (int n4 = 0; n4 < 16; ++n4) {
            float4 xa[4], xb[4];
#pragma unroll
            for (int a = 0; a < 4; ++a) xa[a] = Xs4[swz4(tg * 4 + a, n4)];
#pragma unroll
            for (int e = 0; e < 4; ++e) xb[e] = Xs4[swz4(sg * 4 + e, n4)];
#pragma unroll
            for (int a = 0; a < 4; ++a)
#pragma unroll
                for (int e = 0; e < 4; ++e) acc[a*4+e] += DOT4(xa[a], xb[e]);
        }
        float* base = Gp + ((size_t)(c * NSL + q) * CC) * CC;
#pragma unroll
        for (int a = 0; a < 4; ++a)
            *reinterpret_cast<float4*>(base + (tg * 4 + a) * CC + sg * 4) =
                make_float4(acc[a*4], acc[a*4+1], acc[a*4+2], acc[a*4+3]);
    }
}

// ---------------------------------------------------------------------------
// K4: segmented chunk scan of rho, fully float4. 512 blocks.
__global__ __launch_bounds__(NTHR) void k_rho(
    const float* __restrict__ M, const float* __restrict__ rho0, float* __restrict__ Rho)
{
    __shared__ float4 ssl[8][32];
    const int b = blockIdx.x, tid = threadIdx.x;
    const int l = tid & 31, seg = tid >> 5;              // 8 segs x 4 chunks
    const int f = b * 32 + l;                            // float4 col, 0..16383
    const float uc  = powf(UDEC, (float)CC);
    const float uc4 = uc * uc * uc * uc;
    const float4* M4 = reinterpret_cast<const float4*>(M);
    float4 mreg[4];
#pragma unroll
    for (int j = 0; j < 4; ++j) mreg[j] = M4[(size_t)(seg * 4 + j) * (DD * NN / 4) + f];
    float4 ss = mreg[0];
#pragma unroll
    for (int j = 1; j < 4; ++j) {
        ss.x = fmaf(ss.x, uc, mreg[j].x); ss.y = fmaf(ss.y, uc, mreg[j].y);
        ss.z = fmaf(ss.z, uc, mreg[j].z); ss.w = fmaf(ss.w, uc, mreg[j].w);
    }
    ssl[seg][l] = ss;
    __syncthreads();
    float4 acc = reinterpret_cast<const float4*>(rho0)[f];
    for (int r = 0; r < seg; ++r) {
        float4 sv = ssl[r][l];
        acc.x = fmaf(acc.x, uc4, sv.x); acc.y = fmaf(acc.y, uc4, sv.y);
        acc.z = fmaf(acc.z, uc4, sv.z); acc.w = fmaf(acc.w, uc4, sv.w);
    }
    float4* R4 = reinterpret_cast<float4*>(Rho);
#pragma unroll
    for (int j = 0; j < 4; ++j) {
        R4[(size_t)(seg * 4 + j) * (DD * NN / 4) + f] = acc;
        acc.x = fmaf(acc.x, uc, mreg[j].x); acc.y = fmaf(acc.y, uc, mreg[j].y);
        acc.z = fmaf(acc.z, uc, mreg[j].z); acc.w = fmaf(acc.w, uc, mreg[j].w);
    }
}

// ---------------------------------------------------------------------------
// K5: Pp[t][d] = sum_n X[t][n]*Rho[d][n], per (chunk, slice, t-half). 1024 blocks.
__global__ __launch_bounds__(NTHR) void k_inter(
    const float* __restrict__ Xp, const float* __restrict__ Bb,
    const float* __restrict__ Rho, float* __restrict__ Pp)
{
    __shared__ float Xs[32 * DD];
    __shared__ float Rs[DD * DD];
    const int b = blockIdx.x, tid = threadIdx.x;
    const int c = b >> 5, q = (b >> 1) & 15, h = b & 1;
    for (int i = tid; i < 32 * SLW / 4; i += NTHR) {
        int s = i >> 4, n4 = i & 15;
        int t = c * CC + h * 32 + s;
        float4 xv = *reinterpret_cast<const float4*>(&Xp[t * NN + q * SLW + n4 * 4]);
        float4 bv = *reinterpret_cast<const float4*>(&Bb[(t >> 3) * NN + q * SLW + n4 * 4]);
        reinterpret_cast<float4*>(Xs)[swz4(s, n4)] = F4ADD(xv, bv);
    }
    for (int i = tid; i < DD * SLW / 4; i += NTHR) {
        int s = i >> 4, n4 = i & 15;
        reinterpret_cast<float4*>(Rs)[swz4(s, n4)] =
            *reinterpret_cast<const float4*>(&Rho[(size_t)(c * DD + s) * NN + q * SLW + n4 * 4]);
    }
    __syncthreads();
    const float4* Xs4 = reinterpret_cast<const float4*>(Xs);
    const float4* Rs4 = reinterpret_cast<const float4*>(Rs);
    const int ti = tid >> 4, dg = tid & 15;
    float acc[8];
#pragma unroll
    for (int k = 0; k < 8; ++k) acc[k] = 0.f;
    for (int n4 = 0; n4 < 16; ++n4) {
        float4 xa[2], rv[4];
#pragma unroll
        for (int a = 0; a < 2; ++a) xa[a] = Xs4[swz4(ti * 2 + a, n4)];
#pragma unroll
        for (int e = 0; e < 4; ++e) rv[e] = Rs4[swz4(dg * 4 + e, n4)];
#pragma unroll
        for (int a = 0; a < 2; ++a)
#pragma unroll
            for (int e = 0; e < 4; ++e) acc[a*4+e] += DOT4(xa[a], rv[e]);
    }
#pragma unroll
    for (int a = 0; a < 2; ++a) {
        int trow = h * 32 + ti * 2 + a;
        *reinterpret_cast<float4*>(
            Pp + (((size_t)(c * NSL + q) * CC) + trow) * DD + dg * 4) =
            make_float4(acc[a*4], acc[a*4+1], acc[a*4+2], acc[a*4+3]);
    }
}

// ---------------------------------------------------------------------------
// K6: a* assembly + LN only. 512 blocks.
__global__ __launch_bounds__(NTHR) void k_astar(
    const float* __restrict__ Gp, const float* __restrict__ Pp,
    const float* __restrict__ temb, const int* __restrict__ toks,
    float* __restrict__ LNA)
{
    __shared__ float Ve[CC * DD];
    __shared__ float Gt[4][CC];
    __shared__ float Pt[4][DD];
    __shared__ float pw[CC + 1];
    const int b = blockIdx.x, tid = threadIdx.x;
    const int c = b >> 4, sub = b & 15;                  // tokens t = sub + 16k, k<4
    if (tid <= CC) pw[tid] = powf(UDEC, (float)tid);
    for (int i = tid; i < CC * DD / 4; i += NTHR) {
        int s = i >> 4, d4 = i & 15;
        reinterpret_cast<float4*>(Ve)[s * 16 + d4] =
            reinterpret_cast<const float4*>(temb + toks[c * CC + s] * DD)[d4];
    }
    {
        int k = tid >> 6, s = tid & 63;
        int t = sub + 16 * k;
        float ag = 0.f, ap = 0.f;
#pragma unroll
        for (int q = 0; q < NSL; ++q) {
            ag += Gp[((size_t)(c * NSL + q) * CC + t) * CC + s];
            ap += Pp[((size_t)(c * NSL + q) * CC + t) * DD + s];
        }
        Gt[k][s] = ag; Pt[k][s] = ap;
    }
    __syncthreads();
    {
        const int tk = tid >> 6, d0 = tid & 63;
        const int t = sub + 16 * tk;
        float a = pw[t] * Pt[tk][d0];
        for (int s = 0; s < t; ++s)
            a = fmaf(pw[t - s] * Gt[tk][s], Ve[s * 64 + d0], a);
        float sum = a;
#pragma unroll
        for (int mm = 1; mm < 64; mm <<= 1) sum += __shfl_xor(sum, mm, 64);
        float mean = sum * (1.f / DD);
        float z = a - mean;
        float vv = z * z;
#pragma unroll
        for (int mm = 1; mm < 64; mm <<= 1) vv += __shfl_xor(vv, mm, 64);
        float inv = 1.f / (sqrtf(vv * (1.f / (DD - 1))) + EPS);
        LNA[(c * CC + t) * DD + d0] = z * inv;
    }
}

// ---------------------------------------------------------------------------
// K7: fused y + v per 4-token tile. 512 blocks. Coalesced Dyq / Et4.
__global__ __launch_bounds__(NTHR) void k_yv(
    const float* __restrict__ LNA, const float* __restrict__ Dyq,
    const float* __restrict__ Xp, const float* __restrict__ Bb,
    const float* __restrict__ Et4, float* __restrict__ ys, float* __restrict__ vs)
{
    __shared__ float L[4][DD];
    __shared__ float Ys[4][NN];          // 16 KB
    __shared__ float pre4[4][4][DD];     // [wave][token][d]
    __shared__ float pre[4][DD + 1];
    __shared__ float mrow[4], srow[4];
    const int tt = blockIdx.x, tid = threadIdx.x;
    if (tid < 64) {
        reinterpret_cast<float4*>(&L[0][0])[tid] =
            reinterpret_cast<const float4*>(LNA + tt * 4 * DD)[tid];
    }
    __syncthreads();
    const float4* dyq4 = reinterpret_cast<const float4*>(Dyq);
    for (int nq = 0; nq < 4; ++nq) {
        const int n = nq * 256 + tid;
        float dyr[DD];
#pragma unroll
        for (int j = 0; j < 16; ++j) {
            float4 v = dyq4[j * NN + n];                 // coalesced
            dyr[4*j] = v.x; dyr[4*j+1] = v.y; dyr[4*j+2] = v.z; dyr[4*j+3] = v.w;
        }
#pragma unroll
        for (int k = 0; k < 4; ++k) {
            const float4* lr = reinterpret_cast<const float4*>(&L[k][0]);
            float a0 = 0.f, a1 = 0.f, a2 = 0.f, a3 = 0.f;
#pragma unroll
            for (int j = 0; j < 16; ++j) {
                float4 v = lr[j];
                a0 += v.x * dyr[4*j];   a1 += v.y * dyr[4*j+1];
                a2 += v.z * dyr[4*j+2]; a3 += v.w * dyr[4*j+3];
            }
            float yc = (a0 + a1) + (a2 + a3);
            int tg = tt * 4 + k;
            float xv = Xp[tg * NN + n] + Bb[(tg >> 3) * NN + n];
            float yv = fmaxf(yc, 0.f) * fmaxf(xv, 0.f);
            ys[tg * NN + n] = yv;
            Ys[k][n] = yv;
        }
    }
    __syncthreads();
    const int w = tid >> 6, d = tid & 63;
    float a0 = 0.f, a1 = 0.f, a2 = 0.f, a3 = 0.f;
    const float4* et = reinterpret_cast<const float4*>(Et4) + (size_t)w * 64 * DD + d;
#pragma unroll 4
    for (int i = 0; i < 64; ++i) {
        float4 ev = et[(size_t)i * DD];                  // coalesced
        const int n4g = (w * 64 + i) * 4;
        float4 y0 = *reinterpret_cast<const float4*>(&Ys[0][n4g]);
        float4 y1 = *reinterpret_cast<const float4*>(&Ys[1][n4g]);
        float4 y2 = *reinterpret_cast<const float4*>(&Ys[2][n4g]);
        float4 y3 = *reinterpret_cast<const float4*>(&Ys[3][n4g]);
        a0 += DOT4(ev, y0); a1 += DOT4(ev, y1);
        a2 += DOT4(ev, y2); a3 += DOT4(ev, y3);
    }
    pre4[w][0][d] = a0; pre4[w][1][d] = a1;
    pre4[w][2][d] = a2; pre4[w][3][d] = a3;
    __syncthreads();
    {
        const int k = tid >> 6, dd = tid & 63;
        pre[k][dd] = pre4[0][k][dd] + pre4[1][k][dd] + pre4[2][k][dd] + pre4[3][k][dd];
    }
    __syncthreads();
    if (tid < 4) {
        float m = 0.f;
#pragma unroll
        for (int dd2 = 0; dd2 < DD; ++dd2) m += pre[tid][dd2];
        m *= (1.f / DD);
        float v = 0.f;
#pragma unroll
        for (int dd2 = 0; dd2 < DD; ++dd2) { float z = pre[tid][dd2] - m; v += z * z; }
        mrow[tid] = m;
        srow[tid] = 1.f / (sqrtf(v * (1.f / (DD - 1))) + EPS);
    }
    __syncthreads();
    {
        int k = tid >> 6, dd = tid & 63;
        vs[(tt * 4 + k) * DD + dd] = (pre[k][dd] - mrow[k]) * srow[k];
    }
}

// ---------------------------------------------------------------------------
extern "C" void kernel_launch(void* const* d_in, const int* in_sizes, int n_in,
                              void* d_out, int out_size, void* d_ws, size_t ws_size,
                              hipStream_t stream) {
    (void)in_sizes; (void)n_in; (void)out_size; (void)ws_size;
    const float* E    = (const float*)d_in[0];   // [D,N]
    const float* Dx   = (const float*)d_in[1];   // [N,D]
    const float* Dy   = (const float*)d_in[2];   // [N,D]
    const float* temb = (const float*)d_in[3];   // [V,D]
    const float* x0   = (const float*)d_in[4];   // [N]
    const float* rho0 = (const float*)d_in[5];   // [D,N]
    const int*   toks = (const int*)d_in[6];     // [T]

    float* ys = (float*)d_out;                   // [T,N]
    float* vs = ys + (size_t)TT * NN;            // [T,D]

    // Workspace ~35.5 MiB. Pp aliases M (M dead after K4; Pp written in K5).
    float* w   = (float*)d_ws;
    float* Xp  = w;                                  // TT*NN         (8 MB)
    float* S   = Xp  + (size_t)TT * NN;              // NC2*NN        (1 MB)
    float* Bb  = S   + (size_t)NC2 * NN;             // NC2*NN        (1 MB)
    float* M   = Bb  + (size_t)NC2 * NN;             // NCH*DD*NN     (8 MB)
    float* Rho = M   + (size_t)NCH * DD * NN;        // NCH*DD*NN     (8 MB)
    float* Gp  = Rho + (size_t)NCH * DD * NN;        // NCH*NSL*CC*CC (8 MB)
    float* LNA = Gp  + (size_t)NCH * NSL * CC * CC;  // TT*DD         (0.5 MB)
    float* Et4 = LNA + (size_t)TT * DD;              // NN*DD         (0.25 MB)
    float* Dxq = Et4 + (size_t)NN * DD;              // NN*DD         (0.25 MB)
    float* Dyq = Dxq + (size_t)NN * DD;              // NN*DD         (0.25 MB)
    float* Pp  = M;                                  // alias

    k_prep <<<dim3(192),       NTHR, 0, stream>>>(E, Et4, Dx, Dxq, Dy, Dyq);
    k_xscan<<<dim3(4 * NC2),   NTHR, 0, stream>>>(Dxq, temb, toks, Xp, S);
    k_base <<<dim3(32),        NTHR, 0, stream>>>(S, x0, Bb);
    k_mgram<<<dim3(NCH*NSL*2), NTHR, 0, stream>>>(Xp, Bb, temb, toks, M, Gp);
    k_rho  <<<dim3(512),       NTHR, 0, stream>>>(M, rho0, Rho);
    k_inter<<<dim3(NCH*NSL*2), NTHR, 0, stream>>>(Xp, Bb, Rho, Pp);
    k_astar<<<dim3(NCH*16),    NTHR, 0, stream>>>(Gp, Pp, temb, toks, LNA);
    k_yv   <<<dim3(TT/4),      NTHR, 0, stream>>>(LNA, Dyq, Xp, Bb, Et4, ys, vs);
}

// Round 9
// 157.412 us; speedup vs baseline: 1.1490x; 1.1490x over previous
//
#include <hip/hip_runtime.h>
#include <math.h>

// Problem constants
#define NN 1024      // N
#define DD 64        // D
#define TT 2048      // T
#define UDEC 0.97f
#define EPS 1e-6f

// rho/a* path chunking
#define CC 64        // chunk length along t
#define NCH 32       // TT/CC
#define NSL 16       // N-slices
#define SLW 64       // NN/NSL
// X prefix-scan chunking
#define C2 8
#define NC2 256      // TT/C2

#define NTHR 256

// Swizzled [R][64] fp32 LDS tile: element (r,c) at float4-block r*16+((c>>2)^(r&15)).
__device__ __forceinline__ int swz4(int r, int c4) { return r * 16 + (c4 ^ (r & 15)); }

#define DOT4(p, q2) ((p).x*(q2).x + (p).y*(q2).y + (p).z*(q2).z + (p).w*(q2).w)
#define F4ADD(a, b) make_float4((a).x+(b).x, (a).y+(b).y, (a).z+(b).z, (a).w+(b).w)

// ---------------------------------------------------------------------------
// K0: one-shot transposes (independent of everything else).
//     blocks 0..63:   E[D][N]  -> Et4 [n4][d] float4
//     blocks 64..127: Dx[N][D] -> Dxq [d4][n] float4
//     blocks 128..191:Dy[N][D] -> Dyq [d4][n] float4
__global__ __launch_bounds__(NTHR) void k_prep(
    const float* __restrict__ E, float* __restrict__ Et4,
    const float* __restrict__ Dx, float* __restrict__ Dxq,
    const float* __restrict__ Dy, float* __restrict__ Dyq)
{
    const int b = blockIdx.x, tid = threadIdx.x;
    if (b < 64) {
        const int fi = b * NTHR + tid;                   // n4*64 + d
        const int n4 = fi >> 6, d = fi & 63;
        reinterpret_cast<float4*>(Et4)[fi] =
            reinterpret_cast<const float4*>(E)[d * (NN / 4) + n4];
    } else if (b < 128) {
        const int fi = (b - 64) * NTHR + tid;            // d4*NN + n
        const int d4 = fi >> 10, n = fi & 1023;
        reinterpret_cast<float4*>(Dxq)[fi] =
            reinterpret_cast<const float4*>(Dx)[n * (DD / 4) + d4];
    } else {
        const int fi = (b - 128) * NTHR + tid;
        const int d4 = fi >> 10, n = fi & 1023;
        reinterpret_cast<float4*>(Dyq)[fi] =
            reinterpret_cast<const float4*>(Dy)[n * (DD / 4) + d4];
    }
}

// ---------------------------------------------------------------------------
// K1: X chunk-scan, chunks of C2=8 tokens. 1024 blocks. Coalesced Dxq preload.
__global__ __launch_bounds__(NTHR) void k_xscan(
    const float* __restrict__ Dxq, const float* __restrict__ temb,
    const int* __restrict__ toks, float* __restrict__ Xp, float* __restrict__ S)
{
    __shared__ float Vs[C2][DD];
    const int b = blockIdx.x, tid = threadIdx.x;
    const int cs = b >> 2, qx = b & 3;
    const int n = qx * 256 + tid;
    for (int i = tid; i < C2 * DD / 4; i += NTHR) {
        int s = i >> 4, d4 = i & 15;
        reinterpret_cast<float4*>(&Vs[s][0])[d4] =
            reinterpret_cast<const float4*>(temb + toks[cs * C2 + s] * DD)[d4];
    }
    __syncthreads();
    float dxr[DD];
    const float4* dxq4 = reinterpret_cast<const float4*>(Dxq);
#pragma unroll
    for (int j = 0; j < 16; ++j) {
        float4 v = dxq4[j * NN + n];                     // 1KB/wave coalesced
        dxr[4*j] = v.x; dxr[4*j+1] = v.y; dxr[4*j+2] = v.z; dxr[4*j+3] = v.w;
    }
    float run = 0.f;
    for (int s = 0; s < C2; ++s) {
        const float4* vr = reinterpret_cast<const float4*>(&Vs[s][0]);
        float a0 = 0.f, a1 = 0.f, a2 = 0.f, a3 = 0.f;
#pragma unroll
        for (int j = 0; j < 16; ++j) {
            float4 v = vr[j];
            a0 += v.x * dxr[4*j];     a1 += v.y * dxr[4*j+1];
            a2 += v.z * dxr[4*j+2];   a3 += v.w * dxr[4*j+3];
        }
        run += fmaxf((a0 + a1) + (a2 + a3), 0.f);
        Xp[(cs * C2 + s) * NN + n] = run;
    }
    S[cs * NN + n] = run;
}

// ---------------------------------------------------------------------------
// K2: segmented scan of 256 chunk totals -> exclusive base Bb. 32 blocks.
__global__ __launch_bounds__(NTHR) void k_base(
    const float* __restrict__ S, const float* __restrict__ x0, float* __restrict__ Bb)
{
    __shared__ float ssl[8][33];
    const int b = blockIdx.x, tid = threadIdx.x;
    const int n_l = tid & 31, seg = tid >> 5;            // 8 segs x 32 chunks
    const int n = b * 32 + n_l;
    float m[32];
#pragma unroll
    for (int j = 0; j < 32; ++j) m[j] = S[(seg * 32 + j) * NN + n];
    float tot = 0.f;
#pragma unroll
    for (int j = 0; j < 32; ++j) tot += m[j];
    ssl[seg][n_l] = tot;
    __syncthreads();
    float acc = x0[n];
    for (int r = 0; r < seg; ++r) acc += ssl[r][n_l];
#pragma unroll
    for (int j = 0; j < 32; ++j) {
        Bb[(seg * 32 + j) * NN + n] = acc;               // exclusive prefix + x0
        acc += m[j];
    }
}

// ---------------------------------------------------------------------------
// K3: per (chunk,slice): role0 = M (rank collapse), role1 = Gram. 1024 blocks.
__global__ __launch_bounds__(NTHR) void k_mgram(
    const float* __restrict__ Xp, const float* __restrict__ Bb,
    const float* __restrict__ temb, const int* __restrict__ toks,
    float* __restrict__ M, float* __restrict__ Gp)
{
    __shared__ float Xs[CC * DD];
    __shared__ float Vw[CC * DD];
    __shared__ float pw[CC + 1];
    const int b = blockIdx.x, tid = threadIdx.x;
    const int c = b >> 5, q = (b >> 1) & 15, role = b & 1;
    if (role == 0 && tid <= CC) pw[tid] = powf(UDEC, (float)tid);
    for (int i = tid; i < CC * SLW / 4; i += NTHR) {
        int s = i >> 4, n4 = i & 15;
        int t = c * CC + s;
        float4 xv = *reinterpret_cast<const float4*>(&Xp[t * NN + q * SLW + n4 * 4]);
        float4 bv = *reinterpret_cast<const float4*>(&Bb[(t >> 3) * NN + q * SLW + n4 * 4]);
        reinterpret_cast<float4*>(Xs)[swz4(s, n4)] = F4ADD(xv, bv);
    }
    __syncthreads();
    if (role == 0) {
        for (int i = tid; i < CC * DD / 4; i += NTHR) {
            int s = i >> 4, d4 = i & 15;
            float4 v = reinterpret_cast<const float4*>(temb + toks[c * CC + s] * DD)[d4];
            float wv = pw[CC - s];
            reinterpret_cast<float4*>(Vw)[swz4(s, d4)] =
                make_float4(v.x * wv, v.y * wv, v.z * wv, v.w * wv);
        }
    }
    __syncthreads();
    const float4* Xs4 = reinterpret_cast<const float4*>(Xs);
    if (role == 0) {
        const int dg = tid >> 4, ng = tid & 15;
        float acc[16];
#pragma unroll
        for (int k = 0; k < 16; ++k) acc[k] = 0.f;
        const float4* Vw4 = reinterpret_cast<const float4*>(Vw);
        for (int s = 0; s < CC; ++s) {
            float4 vw = Vw4[swz4(s, dg)];
            float4 xs = Xs4[swz4(s, ng)];
            acc[0]  += vw.x*xs.x; acc[1]  += vw.x*xs.y; acc[2]  += vw.x*xs.z; acc[3]  += vw.x*xs.w;
            acc[4]  += vw.y*xs.x; acc[5]  += vw.y*xs.y; acc[6]  += vw.y*xs.z; acc[7]  += vw.y*xs.w;
            acc[8]  += vw.z*xs.x; acc[9]  += vw.z*xs.y; acc[10] += vw.z*xs.z; acc[11] += vw.z*xs.w;
            acc[12] += vw.w*xs.x; acc[13] += vw.w*xs.y; acc[14] += vw.w*xs.z; acc[15] += vw.w*xs.w;
        }
#pragma unroll
        for (int a = 0; a < 4; ++a)
            *reinterpret_cast<float4*>(&M[(c * DD + dg * 4 + a) * NN + q * SLW + ng * 4]) =
                make_float4(acc[a*4], acc[a*4+1], acc[a*4+2], acc[a*4+3]);
    } else {
        const int tg = tid >> 4, sg = tid & 15;
        float acc[16];
#pragma unroll
        for (int k = 0; k < 16; ++k) acc[k] = 0.f;
        for (int n4 = 0; n4 < 16; ++n4) {
            float4 xa[4], xb[4];
#pragma unroll
            for (int a = 0; a < 4; ++a) xa[a] = Xs4[swz4(tg * 4 + a, n4)];
#pragma unroll
            for (int e = 0; e < 4; ++e) xb[e] = Xs4[swz4(sg * 4 + e, n4)];
#pragma unroll
            for (int a = 0; a < 4; ++a)
#pragma unroll
                for (int e = 0; e < 4; ++e) acc[a*4+e] += DOT4(xa[a], xb[e]);
        }
        float* base = Gp + ((size_t)(c * NSL + q) * CC) * CC;
#pragma unroll
        for (int a = 0; a < 4; ++a)
            *reinterpret_cast<float4*>(base + (tg * 4 + a) * CC + sg * 4) =
                make_float4(acc[a*4], acc[a*4+1], acc[a*4+2], acc[a*4+3]);
    }
}

// ---------------------------------------------------------------------------
// K4: segmented chunk scan of rho, fully float4. 512 blocks.
__global__ __launch_bounds__(NTHR) void k_rho(
    const float* __restrict__ M, const float* __restrict__ rho0, float* __restrict__ Rho)
{
    __shared__ float4 ssl[8][32];
    const int b = blockIdx.x, tid = threadIdx.x;
    const int l = tid & 31, seg = tid >> 5;              // 8 segs x 4 chunks
    const int f = b * 32 + l;                            // float4 col, 0..16383
    const float uc  = powf(UDEC, (float)CC);
    const float uc4 = uc * uc * uc * uc;
    const float4* M4 = reinterpret_cast<const float4*>(M);
    float4 mreg[4];
#pragma unroll
    for (int j = 0; j < 4; ++j) mreg[j] = M4[(size_t)(seg * 4 + j) * (DD * NN / 4) + f];
    float4 ss = mreg[0];
#pragma unroll
    for (int j = 1; j < 4; ++j) {
        ss.x = fmaf(ss.x, uc, mreg[j].x); ss.y = fmaf(ss.y, uc, mreg[j].y);
        ss.z = fmaf(ss.z, uc, mreg[j].z); ss.w = fmaf(ss.w, uc, mreg[j].w);
    }
    ssl[seg][l] = ss;
    __syncthreads();
    float4 acc = reinterpret_cast<const float4*>(rho0)[f];
    for (int r = 0; r < seg; ++r) {
        float4 sv = ssl[r][l];
        acc.x = fmaf(acc.x, uc4, sv.x); acc.y = fmaf(acc.y, uc4, sv.y);
        acc.z = fmaf(acc.z, uc4, sv.z); acc.w = fmaf(acc.w, uc4, sv.w);
    }
    float4* R4 = reinterpret_cast<float4*>(Rho);
#pragma unroll
    for (int j = 0; j < 4; ++j) {
        R4[(size_t)(seg * 4 + j) * (DD * NN / 4) + f] = acc;
        acc.x = fmaf(acc.x, uc, mreg[j].x); acc.y = fmaf(acc.y, uc, mreg[j].y);
        acc.z = fmaf(acc.z, uc, mreg[j].z); acc.w = fmaf(acc.w, uc, mreg[j].w);
    }
}

// ---------------------------------------------------------------------------
// K5: Pp[t][d] = sum_n X[t][n]*Rho[d][n], per (chunk, slice, t-half). 1024 blocks.
__global__ __launch_bounds__(NTHR) void k_inter(
    const float* __restrict__ Xp, const float* __restrict__ Bb,
    const float* __restrict__ Rho, float* __restrict__ Pp)
{
    __shared__ float Xs[32 * DD];
    __shared__ float Rs[DD * DD];
    const int b = blockIdx.x, tid = threadIdx.x;
    const int c = b >> 5, q = (b >> 1) & 15, h = b & 1;
    for (int i = tid; i < 32 * SLW / 4; i += NTHR) {
        int s = i >> 4, n4 = i & 15;
        int t = c * CC + h * 32 + s;
        float4 xv = *reinterpret_cast<const float4*>(&Xp[t * NN + q * SLW + n4 * 4]);
        float4 bv = *reinterpret_cast<const float4*>(&Bb[(t >> 3) * NN + q * SLW + n4 * 4]);
        reinterpret_cast<float4*>(Xs)[swz4(s, n4)] = F4ADD(xv, bv);
    }
    for (int i = tid; i < DD * SLW / 4; i += NTHR) {
        int s = i >> 4, n4 = i & 15;
        reinterpret_cast<float4*>(Rs)[swz4(s, n4)] =
            *reinterpret_cast<const float4*>(&Rho[(size_t)(c * DD + s) * NN + q * SLW + n4 * 4]);
    }
    __syncthreads();
    const float4* Xs4 = reinterpret_cast<const float4*>(Xs);
    const float4* Rs4 = reinterpret_cast<const float4*>(Rs);
    const int ti = tid >> 4, dg = tid & 15;
    float acc[8];
#pragma unroll
    for (int k = 0; k < 8; ++k) acc[k] = 0.f;
    for (int n4 = 0; n4 < 16; ++n4) {
        float4 xa[2], rv[4];
#pragma unroll
        for (int a = 0; a < 2; ++a) xa[a] = Xs4[swz4(ti * 2 + a, n4)];
#pragma unroll
        for (int e = 0; e < 4; ++e) rv[e] = Rs4[swz4(dg * 4 + e, n4)];
#pragma unroll
        for (int a = 0; a < 2; ++a)
#pragma unroll
            for (int e = 0; e < 4; ++e) acc[a*4+e] += DOT4(xa[a], rv[e]);
    }
#pragma unroll
    for (int a = 0; a < 2; ++a) {
        int trow = h * 32 + ti * 2 + a;
        *reinterpret_cast<float4*>(
            Pp + (((size_t)(c * NSL + q) * CC) + trow) * DD + dg * 4) =
            make_float4(acc[a*4], acc[a*4+1], acc[a*4+2], acc[a*4+3]);
    }
}

// ---------------------------------------------------------------------------
// K6: a* assembly + LN only. 512 blocks.
__global__ __launch_bounds__(NTHR) void k_astar(
    const float* __restrict__ Gp, const float* __restrict__ Pp,
    const float* __restrict__ temb, const int* __restrict__ toks,
    float* __restrict__ LNA)
{
    __shared__ float Ve[CC * DD];
    __shared__ float Gt[4][CC];
    __shared__ float Pt[4][DD];
    __shared__ float pw[CC + 1];
    const int b = blockIdx.x, tid = threadIdx.x;
    const int c = b >> 4, sub = b & 15;                  // tokens t = sub + 16k, k<4
    if (tid <= CC) pw[tid] = powf(UDEC, (float)tid);
    for (int i = tid; i < CC * DD / 4; i += NTHR) {
        int s = i >> 4, d4 = i & 15;
        reinterpret_cast<float4*>(Ve)[s * 16 + d4] =
            reinterpret_cast<const float4*>(temb + toks[c * CC + s] * DD)[d4];
    }
    {
        int k = tid >> 6, s = tid & 63;
        int t = sub + 16 * k;
        float ag = 0.f, ap = 0.f;
#pragma unroll
        for (int q = 0; q < NSL; ++q) {
            ag += Gp[((size_t)(c * NSL + q) * CC + t) * CC + s];
            ap += Pp[((size_t)(c * NSL + q) * CC + t) * DD + s];
        }
        Gt[k][s] = ag; Pt[k][s] = ap;
    }
    __syncthreads();
    {
        const int tk = tid >> 6, d0 = tid & 63;
        const int t = sub + 16 * tk;
        float a = pw[t] * Pt[tk][d0];
        for (int s = 0; s < t; ++s)
            a = fmaf(pw[t - s] * Gt[tk][s], Ve[s * 64 + d0], a);
        float sum = a;
#pragma unroll
        for (int mm = 1; mm < 64; mm <<= 1) sum += __shfl_xor(sum, mm, 64);
        float mean = sum * (1.f / DD);
        float z = a - mean;
        float vv = z * z;
#pragma unroll
        for (int mm = 1; mm < 64; mm <<= 1) vv += __shfl_xor(vv, mm, 64);
        float inv = 1.f / (sqrtf(vv * (1.f / (DD - 1))) + EPS);
        LNA[(c * CC + t) * DD + d0] = z * inv;
    }
}

// ---------------------------------------------------------------------------
// K7: y[t][n] = relu(dot(LNA[t], Dy[n])) * relu(x[t][n]). grid (4, 256) = 1024.
//     Coalesced Dyq preload (the round-7 k_y's one remaining flaw).
__global__ __launch_bounds__(NTHR) void k_y(
    const float* __restrict__ LNA, const float* __restrict__ Dyq,
    const float* __restrict__ Xp, const float* __restrict__ Bb,
    float* __restrict__ ys)
{
    __shared__ float L[8][DD];
    const int tt = blockIdx.y;                       // 8-token tile
    const int n  = blockIdx.x * 256 + threadIdx.x;
    for (int i = threadIdx.x; i < 8 * DD / 4; i += NTHR)
        reinterpret_cast<float4*>(&L[0][0])[i] =
            reinterpret_cast<const float4*>(LNA + tt * 8 * DD)[i];
    __syncthreads();
    float dyr[DD];
    const float4* dyq4 = reinterpret_cast<const float4*>(Dyq);
#pragma unroll
    for (int j = 0; j < 16; ++j) {
        float4 v = dyq4[j * NN + n];                 // 1KB/wave coalesced
        dyr[4*j] = v.x; dyr[4*j+1] = v.y; dyr[4*j+2] = v.z; dyr[4*j+3] = v.w;
    }
#pragma unroll
    for (int t = 0; t < 8; ++t) {
        const float4* lr = reinterpret_cast<const float4*>(&L[t][0]);
        float a0 = 0.f, a1 = 0.f, a2 = 0.f, a3 = 0.f;
#pragma unroll
        for (int j = 0; j < 16; ++j) {
            float4 v = lr[j];
            a0 += v.x * dyr[4*j];   a1 += v.y * dyr[4*j+1];
            a2 += v.z * dyr[4*j+2]; a3 += v.w * dyr[4*j+3];
        }
        float yc = (a0 + a1) + (a2 + a3);
        int tg = tt * 8 + t;
        float xv = Xp[tg * NN + n] + Bb[(tg >> 3) * NN + n];
        ys[tg * NN + n] = fmaxf(yc, 0.f) * fmaxf(xv, 0.f);
    }
}

// ---------------------------------------------------------------------------
// K8: vs[t] = LN(E @ y[t]) via transposed Et4, split-K across waves. 512 blocks.
//     Low VGPR (~36), proven ~5us in rounds 6-7.
__global__ __launch_bounds__(NTHR) void k_v(
    const float* __restrict__ ys, const float* __restrict__ Et4, float* __restrict__ vs)
{
    __shared__ float Ys[4][NN];          // 16 KB
    __shared__ float pre4[4][4][DD];     // [wave][token][d]
    __shared__ float pre[4][DD + 1];
    __shared__ float mrow[4], srow[4];
    const int tt = blockIdx.x, tid = threadIdx.x;
    for (int i = tid; i < NN; i += NTHR)
        reinterpret_cast<float4*>(&Ys[0][0])[i] =
            reinterpret_cast<const float4*>(ys + (size_t)tt * 4 * NN)[i];
    __syncthreads();
    const int w = tid >> 6, d = tid & 63;
    float a0 = 0.f, a1 = 0.f, a2 = 0.f, a3 = 0.f;
    const float4* et = reinterpret_cast<const float4*>(Et4) + (size_t)w * 64 * DD + d;
#pragma unroll 4
    for (int i = 0; i < 64; ++i) {
        float4 ev = et[(size_t)i * DD];              // coalesced
        const int n4g = (w * 64 + i) * 4;
        float4 y0 = *reinterpret_cast<const float4*>(&Ys[0][n4g]);
        float4 y1 = *reinterpret_cast<const float4*>(&Ys[1][n4g]);
        float4 y2 = *reinterpret_cast<const float4*>(&Ys[2][n4g]);
        float4 y3 = *reinterpret_cast<const float4*>(&Ys[3][n4g]);
        a0 += DOT4(ev, y0); a1 += DOT4(ev, y1);
        a2 += DOT4(ev, y2); a3 += DOT4(ev, y3);
    }
    pre4[w][0][d] = a0; pre4[w][1][d] = a1;
    pre4[w][2][d] = a2; pre4[w][3][d] = a3;
    __syncthreads();
    {
        const int k = tid >> 6, dd = tid & 63;
        pre[k][dd] = pre4[0][k][dd] + pre4[1][k][dd] + pre4[2][k][dd] + pre4[3][k][dd];
    }
    __syncthreads();
    if (tid < 4) {
        float m = 0.f;
#pragma unroll
        for (int dd2 = 0; dd2 < DD; ++dd2) m += pre[tid][dd2];
        m *= (1.f / DD);
        float v = 0.f;
#pragma unroll
        for (int dd2 = 0; dd2 < DD; ++dd2) { float z = pre[tid][dd2] - m; v += z * z; }
        mrow[tid] = m;
        srow[tid] = 1.f / (sqrtf(v * (1.f / (DD - 1))) + EPS);
    }
    __syncthreads();
    {
        int k = tid >> 6, dd = tid & 63;
        vs[(tt * 4 + k) * DD + dd] = (pre[k][dd] - mrow[k]) * srow[k];
    }
}

// ---------------------------------------------------------------------------
extern "C" void kernel_launch(void* const* d_in, const int* in_sizes, int n_in,
                              void* d_out, int out_size, void* d_ws, size_t ws_size,
                              hipStream_t stream) {
    (void)in_sizes; (void)n_in; (void)out_size; (void)ws_size;
    const float* E    = (const float*)d_in[0];   // [D,N]
    const float* Dx   = (const float*)d_in[1];   // [N,D]
    const float* Dy   = (const float*)d_in[2];   // [N,D]
    const float* temb = (const float*)d_in[3];   // [V,D]
    const float* x0   = (const float*)d_in[4];   // [N]
    const float* rho0 = (const float*)d_in[5];   // [D,N]
    const int*   toks = (const int*)d_in[6];     // [T]

    float* ys = (float*)d_out;                   // [T,N]
    float* vs = ys + (size_t)TT * NN;            // [T,D]

    // Workspace ~35.5 MiB. Pp aliases M (M dead after K4; Pp written in K5).
    float* w   = (float*)d_ws;
    float* Xp  = w;                                  // TT*NN         (8 MB)
    float* S   = Xp  + (size_t)TT * NN;              // NC2*NN        (1 MB)
    float* Bb  = S   + (size_t)NC2 * NN;             // NC2*NN        (1 MB)
    float* M   = Bb  + (size_t)NC2 * NN;             // NCH*DD*NN     (8 MB)
    float* Rho = M   + (size_t)NCH * DD * NN;        // NCH*DD*NN     (8 MB)
    float* Gp  = Rho + (size_t)NCH * DD * NN;        // NCH*NSL*CC*CC (8 MB)
    float* LNA = Gp  + (size_t)NCH * NSL * CC * CC;  // TT*DD         (0.5 MB)
    float* Et4 = LNA + (size_t)TT * DD;              // NN*DD         (0.25 MB)
    float* Dxq = Et4 + (size_t)NN * DD;              // NN*DD         (0.25 MB)
    float* Dyq = Dxq + (size_t)NN * DD;              // NN*DD         (0.25 MB)
    float* Pp  = M;                                  // alias

    k_prep <<<dim3(192),       NTHR, 0, stream>>>(E, Et4, Dx, Dxq, Dy, Dyq);
    k_xscan<<<dim3(4 * NC2),   NTHR, 0, stream>>>(Dxq, temb, toks, Xp, S);
    k_base <<<dim3(32),        NTHR, 0, stream>>>(S, x0, Bb);
    k_mgram<<<dim3(NCH*NSL*2), NTHR, 0, stream>>>(Xp, Bb, temb, toks, M, Gp);
    k_rho  <<<dim3(512),       NTHR, 0, stream>>>(M, rho0, Rho);
    k_inter<<<dim3(NCH*NSL*2), NTHR, 0, stream>>>(Xp, Bb, Rho, Pp);
    k_astar<<<dim3(NCH*16),    NTHR, 0, stream>>>(Gp, Pp, temb, toks, LNA);
    k_y    <<<dim3(4, TT/8),   NTHR, 0, stream>>>(LNA, Dyq, Xp, Bb, ys);
    k_v    <<<dim3(TT/4),      NTHR, 0, stream>>>(ys, Et4, vs);
}